// Round 1
// baseline (94.339 us; speedup 1.0000x reference)
//
#include <hip/hip_runtime.h>
#include <stdint.h>

typedef __bf16 bf16x8 __attribute__((ext_vector_type(8)));
typedef float  f32x4  __attribute__((ext_vector_type(4)));

#define NB 8
#define NT 2048
#define NC 1024
#define NH 64

#define WSWZ_BYTES (32 * 12 * 64 * 8 * 2)   // 384 KB swizzled W frags
#define QK_BYTES   (NB * NT * NH * 2)       // 2 MB each for Q, K, V^T (bf16)

#define SOFTMAX_SC 0.18033688011112042f     // 0.125 * log2(e)

// ---------------------------------------------------------------------------
// Kernel 0: swizzle concat(Wq,Wk,Wv) [1024][192] f32 -> bf16 MFMA B-fragments.
// Layout: wswz[((kb*12 + nf)*64 + lane)*8 + j] = W3[kb*32 + (lane>>4)*8 + j][nf*16 + (lane&15)]
__global__ __launch_bounds__(64) void sdpa_prep_w(
    const float* __restrict__ Wq, const float* __restrict__ Wk,
    const float* __restrict__ Wv, __bf16* __restrict__ wswz) {
  const int blk = blockIdx.x;            // 384 = 32 kb * 12 nf
  const int kb = blk / 12, nf = blk % 12;
  const int l = threadIdx.x;
  const float* W = (nf < 4) ? Wq : ((nf < 8) ? Wk : Wv);
  const int col = ((nf & 3) << 4) + (l & 15);
  const int c0 = kb * 32 + ((l >> 4) << 3);
  union { __bf16 h[8]; uint4 u; } pk;
#pragma unroll
  for (int j = 0; j < 8; ++j) pk.h[j] = (__bf16)W[(size_t)(c0 + j) * NH + col];
  *reinterpret_cast<uint4*>(wswz + ((size_t)blk * 64 + l) * 8) = pk.u;
}

// ---------------------------------------------------------------------------
// Kernel 1: QKV projection. M=16384, K=1024, N=192. BM=32, 4 waves/block,
// wave w owns n-cols [48w, 48w+48). Writes Q,K row-major bf16, V transposed.
__global__ __launch_bounds__(256) void sdpa_qkv(
    const float* __restrict__ x, const __bf16* __restrict__ wswz,
    __bf16* __restrict__ Qb, __bf16* __restrict__ Kb, __bf16* __restrict__ VTb) {
  __shared__ __attribute__((aligned(16))) __bf16 xa[32 * 64];   // XOR-swizzled x tile
  __shared__ __attribute__((aligned(16))) __bf16 vt[64 * 40];   // V^T transpose buffer
  const int tid = threadIdx.x;
  const int w = tid >> 6, l = tid & 63;
  const int r0 = blockIdx.x * 32;
  const f32x4 z = {0.f, 0.f, 0.f, 0.f};
  f32x4 acc[2][3] = {{z, z, z}, {z, z, z}};
  const int srow = tid >> 3;
  const int scol = (tid & 7) * 8;
  char* xab = reinterpret_cast<char*>(xa);
  const float* xp = x + (size_t)(r0 + srow) * NC + scol;
  const int swaddr = (srow * 128 + scol * 2) ^ ((srow & 7) << 4);

  for (int ks = 0; ks < 16; ++ks) {
    float4 f0 = *reinterpret_cast<const float4*>(xp + ks * 64);
    float4 f1 = *reinterpret_cast<const float4*>(xp + ks * 64 + 4);
    union { __bf16 h[8]; uint4 u; } pk;
    pk.h[0] = (__bf16)f0.x; pk.h[1] = (__bf16)f0.y;
    pk.h[2] = (__bf16)f0.z; pk.h[3] = (__bf16)f0.w;
    pk.h[4] = (__bf16)f1.x; pk.h[5] = (__bf16)f1.y;
    pk.h[6] = (__bf16)f1.z; pk.h[7] = (__bf16)f1.w;
    __syncthreads();                       // previous iteration's reads done
    *reinterpret_cast<uint4*>(xab + swaddr) = pk.u;
    __syncthreads();                       // tile visible
#pragma unroll
    for (int kc = 0; kc < 2; ++kc) {
      bf16x8 a[2];
#pragma unroll
      for (int mf = 0; mf < 2; ++mf) {
        const int row = mf * 16 + (l & 15);
        const int addr = (row * 128 + kc * 64 + ((l >> 4) << 4)) ^ ((row & 7) << 4);
        a[mf] = *reinterpret_cast<const bf16x8*>(xab + addr);
      }
#pragma unroll
      for (int nfl = 0; nfl < 3; ++nfl) {
        const bf16x8 bfr = *reinterpret_cast<const bf16x8*>(
            wswz + (((size_t)(2 * ks + kc) * 12 + (w * 3 + nfl)) * 64 + l) * 8);
#pragma unroll
        for (int mf = 0; mf < 2; ++mf)
          acc[mf][nfl] = __builtin_amdgcn_mfma_f32_16x16x32_bf16(a[mf], bfr, acc[mf][nfl], 0, 0, 0);
      }
    }
  }

  const int batch = r0 >> 11;
  const int t0 = r0 & (NT - 1);
#pragma unroll
  for (int mf = 0; mf < 2; ++mf)
#pragma unroll
    for (int nfl = 0; nfl < 3; ++nfl) {
      const int n16 = w * 3 + nfl;         // 0..11
      const int tensor = n16 >> 2;         // 0=Q 1=K 2=V
      const int col = ((n16 & 3) << 4) + (l & 15);
      const int qrow = r0 + mf * 16 + ((l >> 4) << 2);
      if (tensor == 0) {
#pragma unroll
        for (int r = 0; r < 4; ++r)
          Qb[(size_t)(qrow + r) * NH + col] = (__bf16)acc[mf][nfl][r];
      } else if (tensor == 1) {
#pragma unroll
        for (int r = 0; r < 4; ++r)
          Kb[(size_t)(qrow + r) * NH + col] = (__bf16)acc[mf][nfl][r];
      } else {
        // V: stage transposed in LDS (row = d, col = local t), 4 q packed per write
        uint2 pv;
        unsigned short b0 = __builtin_bit_cast(unsigned short, (__bf16)acc[mf][nfl][0]);
        unsigned short b1 = __builtin_bit_cast(unsigned short, (__bf16)acc[mf][nfl][1]);
        unsigned short b2 = __builtin_bit_cast(unsigned short, (__bf16)acc[mf][nfl][2]);
        unsigned short b3 = __builtin_bit_cast(unsigned short, (__bf16)acc[mf][nfl][3]);
        pv.x = (unsigned)b0 | ((unsigned)b1 << 16);
        pv.y = (unsigned)b2 | ((unsigned)b3 << 16);
        const int qloc = mf * 16 + ((l >> 4) << 2);
        *reinterpret_cast<uint2*>(reinterpret_cast<char*>(vt) + (col * 40 + qloc) * 2) = pv;
      }
    }
  __syncthreads();
  {
    const int d = tid >> 2, seg = tid & 3;
    uint4 val = *reinterpret_cast<const uint4*>(
        reinterpret_cast<const char*>(vt) + (d * 40 + seg * 8) * 2);
    *reinterpret_cast<uint4*>(VTb + (size_t)(batch * 64 + d) * NT + t0 + seg * 8) = val;
  }
}

// ---------------------------------------------------------------------------
// Kernel 2: causal flash attention. 1 wave per block, 16 q rows per wave,
// KV tiles of 32. Each block processes q-tile pair (p, 127-p) sequentially
// -> exactly 65 KV steps per block (perfect balance).
#define LOAD_KV(KT, BK, BV) do {                                              \
    const __bf16* kp_ = Kp + (size_t)((KT) * 32 + lq) * NH + lg * 8;          \
    BK[0] = *reinterpret_cast<const bf16x8*>(kp_);                            \
    BK[1] = *reinterpret_cast<const bf16x8*>(kp_ + 32);                       \
    BK[2] = *reinterpret_cast<const bf16x8*>(kp_ + 16 * NH);                  \
    BK[3] = *reinterpret_cast<const bf16x8*>(kp_ + 16 * NH + 32);             \
    const __bf16* vp_ = Vp + (size_t)lq * NT + (KT) * 32 + lg * 8;            \
    BV[0] = *reinterpret_cast<const bf16x8*>(vp_);                            \
    BV[1] = *reinterpret_cast<const bf16x8*>(vp_ + 16 * NT);                  \
    BV[2] = *reinterpret_cast<const bf16x8*>(vp_ + 32 * NT);                  \
    BV[3] = *reinterpret_cast<const bf16x8*>(vp_ + 48 * NT);                  \
  } while (0)

__global__ __launch_bounds__(64) void sdpa_attn(
    const __bf16* __restrict__ Qb, const __bf16* __restrict__ Kb,
    const __bf16* __restrict__ VTb, float* __restrict__ out) {
  __shared__ __attribute__((aligned(16))) __bf16 pbuf[16 * 40];  // padded: row 80B
  const int l = threadIdx.x;
  const int b = blockIdx.x >> 6;
  const int p = blockIdx.x & 63;
  const __bf16* Qp = Qb + (size_t)b * NT * NH;
  const __bf16* Kp = Kb + (size_t)b * NT * NH;
  const __bf16* Vp = VTb + (size_t)b * NH * NT;
  float* op = out + (size_t)b * NT * NH;
  const int lq = l & 15, lg = l >> 4;
  const f32x4 z = {0.f, 0.f, 0.f, 0.f};

#pragma unroll
  for (int half = 0; half < 2; ++half) {
    const int qt = half ? (127 - p) : p;
    const int q0 = qt * 16;
    bf16x8 aq[2];
#pragma unroll
    for (int kc = 0; kc < 2; ++kc)
      aq[kc] = *reinterpret_cast<const bf16x8*>(Qp + (size_t)(q0 + lq) * NH + kc * 32 + lg * 8);
    f32x4 o[4] = {z, z, z, z};
    float m[4] = {-1e30f, -1e30f, -1e30f, -1e30f};
    float ls[4] = {0.f, 0.f, 0.f, 0.f};
    const int nkt = (qt >> 1) + 1;
    bf16x8 bk[4], bv[4], nbk[4], nbv[4];
    LOAD_KV(0, bk, bv);

    for (int kt = 0; kt < nkt; ++kt) {
      const bool more = (kt + 1 < nkt);
      if (more) LOAD_KV(kt + 1, nbk, nbv);   // prefetch next tile (hides L2 latency)

      f32x4 s0 = __builtin_amdgcn_mfma_f32_16x16x32_bf16(aq[0], bk[0], z, 0, 0, 0);
      s0 = __builtin_amdgcn_mfma_f32_16x16x32_bf16(aq[1], bk[1], s0, 0, 0, 0);
      f32x4 s1 = __builtin_amdgcn_mfma_f32_16x16x32_bf16(aq[0], bk[2], z, 0, 0, 0);
      s1 = __builtin_amdgcn_mfma_f32_16x16x32_bf16(aq[1], bk[3], s1, 0, 0, 0);

      if (kt == (qt >> 1)) {                 // diagonal tile: causal mask
        const int kbase = kt * 32 + lq;
        const int qrow = q0 + lg * 4;
#pragma unroll
        for (int r = 0; r < 4; ++r) {
          if (kbase > qrow + r) s0[r] = -1e30f;
          if (kbase + 16 > qrow + r) s1[r] = -1e30f;
        }
      }

      float esc[4];
#pragma unroll
      for (int r = 0; r < 4; ++r) {
        float tm = fmaxf(s0[r], s1[r]);
        tm = fmaxf(tm, __shfl_xor(tm, 1));
        tm = fmaxf(tm, __shfl_xor(tm, 2));
        tm = fmaxf(tm, __shfl_xor(tm, 4));
        tm = fmaxf(tm, __shfl_xor(tm, 8));
        const float mn = fmaxf(m[r], tm);
        esc[r] = exp2f((m[r] - mn) * SOFTMAX_SC);
        m[r] = mn;
        const float p0 = exp2f((s0[r] - mn) * SOFTMAX_SC);
        const float p1 = exp2f((s1[r] - mn) * SOFTMAX_SC);
        s0[r] = p0; s1[r] = p1;
        float rs = p0 + p1;
        rs += __shfl_xor(rs, 1);
        rs += __shfl_xor(rs, 2);
        rs += __shfl_xor(rs, 4);
        rs += __shfl_xor(rs, 8);
        ls[r] = ls[r] * esc[r] + rs;
      }
#pragma unroll
      for (int df = 0; df < 4; ++df)
#pragma unroll
        for (int r = 0; r < 4; ++r) o[df][r] *= esc[r];

      // P (f32, D-layout) -> LDS -> A-fragment layout (bf16)
#pragma unroll
      for (int r = 0; r < 4; ++r) {
        pbuf[(lg * 4 + r) * 40 + lq] = (__bf16)s0[r];
        pbuf[(lg * 4 + r) * 40 + lq + 16] = (__bf16)s1[r];
      }
      const bf16x8 pa = *reinterpret_cast<const bf16x8*>(&pbuf[lq * 40 + lg * 8]);
#pragma unroll
      for (int df = 0; df < 4; ++df)
        o[df] = __builtin_amdgcn_mfma_f32_16x16x32_bf16(pa, bv[df], o[df], 0, 0, 0);

      if (more) {
#pragma unroll
        for (int i = 0; i < 4; ++i) { bk[i] = nbk[i]; bv[i] = nbv[i]; }
      }
    }
#pragma unroll
    for (int r = 0; r < 4; ++r) {
      const float inv = 1.0f / ls[r];
      const int qrow = q0 + lg * 4 + r;
#pragma unroll
      for (int df = 0; df < 4; ++df)
        op[(size_t)qrow * NH + df * 16 + lq] = o[df][r] * inv;
    }
  }
}

// ---------------------------------------------------------------------------
extern "C" void kernel_launch(void* const* d_in, const int* in_sizes, int n_in,
                              void* d_out, int out_size, void* d_ws, size_t ws_size,
                              hipStream_t stream) {
  const float* x  = (const float*)d_in[0];
  const float* Wq = (const float*)d_in[1];
  const float* Wk = (const float*)d_in[2];
  const float* Wv = (const float*)d_in[3];
  char* ws = (char*)d_ws;
  __bf16* wswz = (__bf16*)(ws);
  __bf16* Qb   = (__bf16*)(ws + WSWZ_BYTES);
  __bf16* Kb   = (__bf16*)(ws + WSWZ_BYTES + QK_BYTES);
  __bf16* VTb  = (__bf16*)(ws + WSWZ_BYTES + 2 * (size_t)QK_BYTES);
  float* out = (float*)d_out;

  sdpa_prep_w<<<dim3(384), dim3(64), 0, stream>>>(Wq, Wk, Wv, wswz);
  sdpa_qkv<<<dim3(512), dim3(256), 0, stream>>>(x, wswz, Qb, Kb, VTb);
  sdpa_attn<<<dim3(NB * 64), dim3(64), 0, stream>>>(Qb, Kb, VTb, out);
}

// Round 2
// 82.801 us; speedup vs baseline: 1.1394x; 1.1394x over previous
//
#include <hip/hip_runtime.h>
#include <stdint.h>

typedef __bf16 bf16x8 __attribute__((ext_vector_type(8)));
typedef float  f32x4  __attribute__((ext_vector_type(4)));

#define NB 8
#define NT 2048
#define NC 1024
#define NH 64

#define WSWZ_BYTES (32 * 12 * 64 * 8 * 2)   // 384 KB swizzled W frags
#define QK_BYTES   (NB * NT * NH * 2)       // 2 MB each for Q, K, V^T (bf16)

// KV-split attention: segments of 8 KV-tiles (256 kv). Per batch:
// q-tile qt (0..127) has nseg = (qt>>4)+1 segments; sum = 576/batch.
#define SEG_PER_B 576
#define SLOTS     (NB * SEG_PER_B)          // 4608
#define PO_OFF    (WSWZ_BYTES + 3 * QK_BYTES)
#define PO_BYTES  (SLOTS * 16 * 64 * 2)     // bf16 partial O
#define PM_OFF    (PO_OFF + PO_BYTES)
#define PM_BYTES  (SLOTS * 16 * 4)
#define PL_OFF    (PM_OFF + PM_BYTES)

#define SOFTMAX_SC 0.18033688011112042f     // 0.125 * log2(e)

// ---------------------------------------------------------------------------
// Kernel 0: swizzle concat(Wq,Wk,Wv) [1024][192] f32 -> bf16 MFMA B-fragments.
__global__ __launch_bounds__(64) void sdpa_prep_w(
    const float* __restrict__ Wq, const float* __restrict__ Wk,
    const float* __restrict__ Wv, __bf16* __restrict__ wswz) {
  const int blk = blockIdx.x;            // 384 = 32 kb * 12 nf
  const int kb = blk / 12, nf = blk % 12;
  const int l = threadIdx.x;
  const float* W = (nf < 4) ? Wq : ((nf < 8) ? Wk : Wv);
  const int col = ((nf & 3) << 4) + (l & 15);
  const int c0 = kb * 32 + ((l >> 4) << 3);
  union { __bf16 h[8]; uint4 u; } pk;
#pragma unroll
  for (int j = 0; j < 8; ++j) pk.h[j] = (__bf16)W[(size_t)(c0 + j) * NH + col];
  *reinterpret_cast<uint4*>(wswz + ((size_t)blk * 64 + l) * 8) = pk.u;
}

// ---------------------------------------------------------------------------
// Kernel 1: QKV projection. M=16384, K=1024, N=192. BM=32, 4 waves/block.
__global__ __launch_bounds__(256) void sdpa_qkv(
    const float* __restrict__ x, const __bf16* __restrict__ wswz,
    __bf16* __restrict__ Qb, __bf16* __restrict__ Kb, __bf16* __restrict__ VTb) {
  __shared__ __attribute__((aligned(16))) __bf16 xa[32 * 64];
  __shared__ __attribute__((aligned(16))) __bf16 vt[64 * 40];
  const int tid = threadIdx.x;
  const int w = tid >> 6, l = tid & 63;
  const int r0 = blockIdx.x * 32;
  const f32x4 z = {0.f, 0.f, 0.f, 0.f};
  f32x4 acc[2][3] = {{z, z, z}, {z, z, z}};
  const int srow = tid >> 3;
  const int scol = (tid & 7) * 8;
  char* xab = reinterpret_cast<char*>(xa);
  const float* xp = x + (size_t)(r0 + srow) * NC + scol;
  const int swaddr = (srow * 128 + scol * 2) ^ ((srow & 7) << 4);

  for (int ks = 0; ks < 16; ++ks) {
    float4 f0 = *reinterpret_cast<const float4*>(xp + ks * 64);
    float4 f1 = *reinterpret_cast<const float4*>(xp + ks * 64 + 4);
    union { __bf16 h[8]; uint4 u; } pk;
    pk.h[0] = (__bf16)f0.x; pk.h[1] = (__bf16)f0.y;
    pk.h[2] = (__bf16)f0.z; pk.h[3] = (__bf16)f0.w;
    pk.h[4] = (__bf16)f1.x; pk.h[5] = (__bf16)f1.y;
    pk.h[6] = (__bf16)f1.z; pk.h[7] = (__bf16)f1.w;
    __syncthreads();
    *reinterpret_cast<uint4*>(xab + swaddr) = pk.u;
    __syncthreads();
#pragma unroll
    for (int kc = 0; kc < 2; ++kc) {
      bf16x8 a[2];
#pragma unroll
      for (int mf = 0; mf < 2; ++mf) {
        const int row = mf * 16 + (l & 15);
        const int addr = (row * 128 + kc * 64 + ((l >> 4) << 4)) ^ ((row & 7) << 4);
        a[mf] = *reinterpret_cast<const bf16x8*>(xab + addr);
      }
#pragma unroll
      for (int nfl = 0; nfl < 3; ++nfl) {
        const bf16x8 bfr = *reinterpret_cast<const bf16x8*>(
            wswz + (((size_t)(2 * ks + kc) * 12 + (w * 3 + nfl)) * 64 + l) * 8);
#pragma unroll
        for (int mf = 0; mf < 2; ++mf)
          acc[mf][nfl] = __builtin_amdgcn_mfma_f32_16x16x32_bf16(a[mf], bfr, acc[mf][nfl], 0, 0, 0);
      }
    }
  }

  const int batch = r0 >> 11;
  const int t0 = r0 & (NT - 1);
#pragma unroll
  for (int mf = 0; mf < 2; ++mf)
#pragma unroll
    for (int nfl = 0; nfl < 3; ++nfl) {
      const int n16 = w * 3 + nfl;
      const int tensor = n16 >> 2;
      const int col = ((n16 & 3) << 4) + (l & 15);
      const int qrow = r0 + mf * 16 + ((l >> 4) << 2);
      if (tensor == 0) {
#pragma unroll
        for (int r = 0; r < 4; ++r)
          Qb[(size_t)(qrow + r) * NH + col] = (__bf16)acc[mf][nfl][r];
      } else if (tensor == 1) {
#pragma unroll
        for (int r = 0; r < 4; ++r)
          Kb[(size_t)(qrow + r) * NH + col] = (__bf16)acc[mf][nfl][r];
      } else {
        uint2 pv;
        unsigned short b0 = __builtin_bit_cast(unsigned short, (__bf16)acc[mf][nfl][0]);
        unsigned short b1 = __builtin_bit_cast(unsigned short, (__bf16)acc[mf][nfl][1]);
        unsigned short b2 = __builtin_bit_cast(unsigned short, (__bf16)acc[mf][nfl][2]);
        unsigned short b3 = __builtin_bit_cast(unsigned short, (__bf16)acc[mf][nfl][3]);
        pv.x = (unsigned)b0 | ((unsigned)b1 << 16);
        pv.y = (unsigned)b2 | ((unsigned)b3 << 16);
        const int qloc = mf * 16 + ((l >> 4) << 2);
        *reinterpret_cast<uint2*>(reinterpret_cast<char*>(vt) + (col * 40 + qloc) * 2) = pv;
      }
    }
  __syncthreads();
  {
    const int d = tid >> 2, seg = tid & 3;
    uint4 val = *reinterpret_cast<const uint4*>(
        reinterpret_cast<const char*>(vt) + (d * 40 + seg * 8) * 2);
    *reinterpret_cast<uint4*>(VTb + (size_t)(batch * 64 + d) * NT + t0 + seg * 8) = val;
  }
}

// ---------------------------------------------------------------------------
// Kernel 2: causal flash attention SEGMENT. 1 wave/block, 16 q rows, KV tiles
// of 32, <=8 tiles per segment. Writes unnormalized partial (o bf16, m, l).
#define LOAD_KV(KT, BK, BV) do {                                              \
    const __bf16* kp_ = Kp + (size_t)((KT) * 32 + lq) * NH + lg * 8;          \
    BK[0] = *reinterpret_cast<const bf16x8*>(kp_);                            \
    BK[1] = *reinterpret_cast<const bf16x8*>(kp_ + 32);                       \
    BK[2] = *reinterpret_cast<const bf16x8*>(kp_ + 16 * NH);                  \
    BK[3] = *reinterpret_cast<const bf16x8*>(kp_ + 16 * NH + 32);             \
    const __bf16* vp_ = Vp + (size_t)lq * NT + (KT) * 32 + lg * 8;            \
    BV[0] = *reinterpret_cast<const bf16x8*>(vp_);                            \
    BV[1] = *reinterpret_cast<const bf16x8*>(vp_ + 16 * NT);                  \
    BV[2] = *reinterpret_cast<const bf16x8*>(vp_ + 32 * NT);                  \
    BV[3] = *reinterpret_cast<const bf16x8*>(vp_ + 48 * NT);                  \
  } while (0)

__global__ __launch_bounds__(64) void sdpa_attn_seg(
    const __bf16* __restrict__ Qb, const __bf16* __restrict__ Kb,
    const __bf16* __restrict__ VTb, __bf16* __restrict__ po,
    float* __restrict__ pm, float* __restrict__ pl) {
  __shared__ __attribute__((aligned(16))) __bf16 pbuf[16 * 40];
  const int l = threadIdx.x;
  const int bid = blockIdx.x;
  const int b = bid / SEG_PER_B;
  const int s = bid - b * SEG_PER_B;
  int g = 0;
#pragma unroll
  for (int gg = 1; gg < 8; ++gg)
    if (8 * gg * (gg + 1) <= s) g = gg;
  const int rem = s - 8 * g * (g + 1);
  const int qdiv = rem / (g + 1);
  const int qt = (g << 4) + qdiv;
  const int seg = rem - qdiv * (g + 1);
  const int nkt = (qt >> 1) + 1;
  const int ndiag = nkt - 1;
  const int kt0 = seg * 8;
  const int kt1 = (kt0 + 8 < nkt) ? (kt0 + 8) : nkt;

  const __bf16* Qp = Qb + (size_t)b * NT * NH;
  const __bf16* Kp = Kb + (size_t)b * NT * NH;
  const __bf16* Vp = VTb + (size_t)b * NH * NT;
  const int lq = l & 15, lg = l >> 4;
  const f32x4 z = {0.f, 0.f, 0.f, 0.f};
  const int q0 = qt * 16;

  bf16x8 aq[2];
#pragma unroll
  for (int kc = 0; kc < 2; ++kc)
    aq[kc] = *reinterpret_cast<const bf16x8*>(Qp + (size_t)(q0 + lq) * NH + kc * 32 + lg * 8);
  bf16x8 ones;
#pragma unroll
  for (int j = 0; j < 8; ++j) ones[j] = (__bf16)1.0f;

  f32x4 o[4] = {z, z, z, z};
  f32x4 ol = z;                                     // row-sums via MFMA
  float m[4] = {-1e30f, -1e30f, -1e30f, -1e30f};
  bf16x8 bk[4], bv[4], nbk[4], nbv[4];
  LOAD_KV(kt0, bk, bv);

  for (int kt = kt0; kt < kt1; ++kt) {
    const bool more = (kt + 1 < kt1);
    if (more) LOAD_KV(kt + 1, nbk, nbv);

    f32x4 s0 = __builtin_amdgcn_mfma_f32_16x16x32_bf16(aq[0], bk[0], z, 0, 0, 0);
    s0 = __builtin_amdgcn_mfma_f32_16x16x32_bf16(aq[1], bk[1], s0, 0, 0, 0);
    f32x4 s1 = __builtin_amdgcn_mfma_f32_16x16x32_bf16(aq[0], bk[2], z, 0, 0, 0);
    s1 = __builtin_amdgcn_mfma_f32_16x16x32_bf16(aq[1], bk[3], s1, 0, 0, 0);

    if (kt == ndiag) {                              // diagonal: causal mask
      const int kbase = kt * 32 + lq;
      const int qrow = q0 + lg * 4;
#pragma unroll
      for (int r = 0; r < 4; ++r) {
        if (kbase > qrow + r) s0[r] = -1e30f;
        if (kbase + 16 > qrow + r) s1[r] = -1e30f;
      }
    }

    float esc[4];
#pragma unroll
    for (int r = 0; r < 4; ++r) {
      float tm = fmaxf(s0[r], s1[r]);
      tm = fmaxf(tm, __shfl_xor(tm, 1));
      tm = fmaxf(tm, __shfl_xor(tm, 2));
      tm = fmaxf(tm, __shfl_xor(tm, 4));
      tm = fmaxf(tm, __shfl_xor(tm, 8));
      const float mn = fmaxf(m[r], tm);
      esc[r] = exp2f((m[r] - mn) * SOFTMAX_SC);
      m[r] = mn;
      s0[r] = exp2f((s0[r] - mn) * SOFTMAX_SC);
      s1[r] = exp2f((s1[r] - mn) * SOFTMAX_SC);
    }
#pragma unroll
    for (int df = 0; df < 4; ++df)
#pragma unroll
      for (int r = 0; r < 4; ++r) o[df][r] *= esc[r];
#pragma unroll
    for (int r = 0; r < 4; ++r) ol[r] *= esc[r];

    // P (f32, D-layout) -> LDS -> A-fragment layout (bf16)
#pragma unroll
    for (int r = 0; r < 4; ++r) {
      pbuf[(lg * 4 + r) * 40 + lq] = (__bf16)s0[r];
      pbuf[(lg * 4 + r) * 40 + lq + 16] = (__bf16)s1[r];
    }
    const bf16x8 pa = *reinterpret_cast<const bf16x8*>(&pbuf[lq * 40 + lg * 8]);
    ol = __builtin_amdgcn_mfma_f32_16x16x32_bf16(pa, ones, ol, 0, 0, 0);
#pragma unroll
    for (int df = 0; df < 4; ++df)
      o[df] = __builtin_amdgcn_mfma_f32_16x16x32_bf16(pa, bv[df], o[df], 0, 0, 0);

    if (more) {
#pragma unroll
      for (int i = 0; i < 4; ++i) { bk[i] = nbk[i]; bv[i] = nbv[i]; }
    }
  }

  // write partials (unnormalized)
  __bf16* pop = po + (size_t)bid * 1024;
#pragma unroll
  for (int r = 0; r < 4; ++r) {
    const int row = lg * 4 + r;
#pragma unroll
    for (int df = 0; df < 4; ++df)
      pop[row * 64 + df * 16 + lq] = (__bf16)o[df][r];
    if (lq == 0) {
      pm[bid * 16 + row] = m[r];
      pl[bid * 16 + row] = ol[r];
    }
  }
}

// ---------------------------------------------------------------------------
// Kernel 3: combine <=8 segments per q-tile, normalize, write f32 out.
__global__ __launch_bounds__(128) void sdpa_combine(
    const __bf16* __restrict__ po, const float* __restrict__ pm,
    const float* __restrict__ pl, float* __restrict__ out) {
  const int blk = blockIdx.x;              // 1024: b*128 + qt
  const int b = blk >> 7, qt = blk & 127;
  const int g = qt >> 4, nseg = g + 1;
  const int base = b * SEG_PER_B + 8 * g * (g + 1) + (qt - (g << 4)) * nseg;
  const int t = threadIdx.x;
  const int r = t >> 3, dc = (t & 7) << 3;

  float M = -1e30f;
  for (int s = 0; s < nseg; ++s) M = fmaxf(M, pm[(base + s) * 16 + r]);
  float L = 0.f;
  float acc[8] = {0.f, 0.f, 0.f, 0.f, 0.f, 0.f, 0.f, 0.f};
  for (int s = 0; s < nseg; ++s) {
    const int slot = base + s;
    const float w = exp2f((pm[slot * 16 + r] - M) * SOFTMAX_SC);
    L += pl[slot * 16 + r] * w;
    const bf16x8 v = *reinterpret_cast<const bf16x8*>(po + (size_t)slot * 1024 + r * 64 + dc);
#pragma unroll
    for (int j = 0; j < 8; ++j) acc[j] += w * (float)v[j];
  }
  const float inv = 1.f / L;
  float4 o0 = {acc[0] * inv, acc[1] * inv, acc[2] * inv, acc[3] * inv};
  float4 o1 = {acc[4] * inv, acc[5] * inv, acc[6] * inv, acc[7] * inv};
  float* dst = out + ((size_t)b * NT + qt * 16 + r) * NH + dc;
  *reinterpret_cast<float4*>(dst) = o0;
  *reinterpret_cast<float4*>(dst + 4) = o1;
}

// ---------------------------------------------------------------------------
extern "C" void kernel_launch(void* const* d_in, const int* in_sizes, int n_in,
                              void* d_out, int out_size, void* d_ws, size_t ws_size,
                              hipStream_t stream) {
  const float* x  = (const float*)d_in[0];
  const float* Wq = (const float*)d_in[1];
  const float* Wk = (const float*)d_in[2];
  const float* Wv = (const float*)d_in[3];
  char* ws = (char*)d_ws;
  __bf16* wswz = (__bf16*)(ws);
  __bf16* Qb   = (__bf16*)(ws + WSWZ_BYTES);
  __bf16* Kb   = (__bf16*)(ws + WSWZ_BYTES + QK_BYTES);
  __bf16* VTb  = (__bf16*)(ws + WSWZ_BYTES + 2 * (size_t)QK_BYTES);
  __bf16* po   = (__bf16*)(ws + PO_OFF);
  float*  pm   = (float*)(ws + PM_OFF);
  float*  pl   = (float*)(ws + PL_OFF);
  float* out = (float*)d_out;

  sdpa_prep_w<<<dim3(384), dim3(64), 0, stream>>>(Wq, Wk, Wv, wswz);
  sdpa_qkv<<<dim3(512), dim3(256), 0, stream>>>(x, wswz, Qb, Kb, VTb);
  sdpa_attn_seg<<<dim3(SLOTS), dim3(64), 0, stream>>>(Qb, Kb, VTb, po, pm, pl);
  sdpa_combine<<<dim3(NB * 128), dim3(128), 0, stream>>>(po, pm, pl, out);
}

// Round 4
// 66.383 us; speedup vs baseline: 1.4211x; 1.2473x over previous
//
#include <hip/hip_runtime.h>
#include <stdint.h>

typedef __bf16 bf16x8 __attribute__((ext_vector_type(8)));
typedef float  f32x4  __attribute__((ext_vector_type(4)));
typedef float  f32x16 __attribute__((ext_vector_type(16)));

#define NB 8
#define NT 2048
#define NC 1024
#define NH 64

#define WSWZ_BYTES (32 * 12 * 64 * 8 * 2)   // 384 KB swizzled W frags
#define QK_BYTES   (NB * NT * NH * 2)       // 2 MB each for Q, K, V^T (bf16)

// 32x32 attention: QBLK=32 (q-tiles 0..63/batch), KVBLK=64, segments of 4 steps.
#define SEG_PER_B 288
#define SLOTS     (NB * SEG_PER_B)          // 2304
#define PO_OFF    (WSWZ_BYTES + 3 * QK_BYTES)
#define PO_BYTES  (SLOTS * 32 * 64 * 2)     // bf16 partial O, [slot][q32][d64]
#define PM_OFF    (PO_OFF + PO_BYTES)
#define PM_BYTES  (SLOTS * 32 * 4)
#define PL_OFF    (PM_OFF + PM_BYTES)

#define SOFTMAX_SC 0.18033688011112042f     // 0.125 * log2(e)
#define MASK_VAL  (-30000.0f)               // safe-range sentinel (no f32 cancellation blowup)
#define MINIT_VAL (-10000.0f)

// ---------------------------------------------------------------------------
__device__ __forceinline__ unsigned cvtpk(float lo, float hi) {
  unsigned r;
  asm("v_cvt_pk_bf16_f32 %0, %1, %2" : "=v"(r) : "v"(lo), "v"(hi));
  return r;
}

// ---------------------------------------------------------------------------
// Kernel 0: swizzle concat(Wq,Wk,Wv) [1024][192] f32 -> bf16 MFMA B-fragments.
__global__ __launch_bounds__(64) void sdpa_prep_w(
    const float* __restrict__ Wq, const float* __restrict__ Wk,
    const float* __restrict__ Wv, __bf16* __restrict__ wswz) {
  const int blk = blockIdx.x;            // 384 = 32 kb * 12 nf
  const int kb = blk / 12, nf = blk % 12;
  const int l = threadIdx.x;
  const float* W = (nf < 4) ? Wq : ((nf < 8) ? Wk : Wv);
  const int col = ((nf & 3) << 4) + (l & 15);
  const int c0 = kb * 32 + ((l >> 4) << 3);
  union { __bf16 h[8]; uint4 u; } pk;
#pragma unroll
  for (int j = 0; j < 8; ++j) pk.h[j] = (__bf16)W[(size_t)(c0 + j) * NH + col];
  *reinterpret_cast<uint4*>(wswz + ((size_t)blk * 64 + l) * 8) = pk.u;
}

// ---------------------------------------------------------------------------
// Kernel 1: QKV projection. M=16384, K=1024, N=192. BM=32, 4 waves/block.
__global__ __launch_bounds__(256) void sdpa_qkv(
    const float* __restrict__ x, const __bf16* __restrict__ wswz,
    __bf16* __restrict__ Qb, __bf16* __restrict__ Kb, __bf16* __restrict__ VTb) {
  __shared__ __attribute__((aligned(16))) __bf16 xa[32 * 64];
  __shared__ __attribute__((aligned(16))) __bf16 vt[64 * 40];
  const int tid = threadIdx.x;
  const int w = tid >> 6, l = tid & 63;
  const int r0 = blockIdx.x * 32;
  const f32x4 z = {0.f, 0.f, 0.f, 0.f};
  f32x4 acc[2][3] = {{z, z, z}, {z, z, z}};
  const int srow = tid >> 3;
  const int scol = (tid & 7) * 8;
  char* xab = reinterpret_cast<char*>(xa);
  const float* xp = x + (size_t)(r0 + srow) * NC + scol;
  const int swaddr = (srow * 128 + scol * 2) ^ ((srow & 7) << 4);

  float4 f0 = *reinterpret_cast<const float4*>(xp);
  float4 f1 = *reinterpret_cast<const float4*>(xp + 4);
  for (int ks = 0; ks < 16; ++ks) {
    union { __bf16 h[8]; uint4 u; } pk;
    pk.h[0] = (__bf16)f0.x; pk.h[1] = (__bf16)f0.y;
    pk.h[2] = (__bf16)f0.z; pk.h[3] = (__bf16)f0.w;
    pk.h[4] = (__bf16)f1.x; pk.h[5] = (__bf16)f1.y;
    pk.h[6] = (__bf16)f1.z; pk.h[7] = (__bf16)f1.w;
    __syncthreads();
    *reinterpret_cast<uint4*>(xab + swaddr) = pk.u;
    __syncthreads();
    if (ks < 15) {                         // prefetch next tile during MFMA
      f0 = *reinterpret_cast<const float4*>(xp + (ks + 1) * 64);
      f1 = *reinterpret_cast<const float4*>(xp + (ks + 1) * 64 + 4);
    }
#pragma unroll
    for (int kc = 0; kc < 2; ++kc) {
      bf16x8 a[2];
#pragma unroll
      for (int mf = 0; mf < 2; ++mf) {
        const int row = mf * 16 + (l & 15);
        const int addr = (row * 128 + kc * 64 + ((l >> 4) << 4)) ^ ((row & 7) << 4);
        a[mf] = *reinterpret_cast<const bf16x8*>(xab + addr);
      }
#pragma unroll
      for (int nfl = 0; nfl < 3; ++nfl) {
        const bf16x8 bfr = *reinterpret_cast<const bf16x8*>(
            wswz + (((size_t)(2 * ks + kc) * 12 + (w * 3 + nfl)) * 64 + l) * 8);
#pragma unroll
        for (int mf = 0; mf < 2; ++mf)
          acc[mf][nfl] = __builtin_amdgcn_mfma_f32_16x16x32_bf16(a[mf], bfr, acc[mf][nfl], 0, 0, 0);
      }
    }
  }

  const int batch = r0 >> 11;
  const int t0 = r0 & (NT - 1);
#pragma unroll
  for (int mf = 0; mf < 2; ++mf)
#pragma unroll
    for (int nfl = 0; nfl < 3; ++nfl) {
      const int n16 = w * 3 + nfl;
      const int tensor = n16 >> 2;
      const int col = ((n16 & 3) << 4) + (l & 15);
      const int qrow = r0 + mf * 16 + ((l >> 4) << 2);
      if (tensor == 0) {
#pragma unroll
        for (int r = 0; r < 4; ++r)
          Qb[(size_t)(qrow + r) * NH + col] = (__bf16)acc[mf][nfl][r];
      } else if (tensor == 1) {
#pragma unroll
        for (int r = 0; r < 4; ++r)
          Kb[(size_t)(qrow + r) * NH + col] = (__bf16)acc[mf][nfl][r];
      } else {
        uint2 pv;
        unsigned short b0 = __builtin_bit_cast(unsigned short, (__bf16)acc[mf][nfl][0]);
        unsigned short b1 = __builtin_bit_cast(unsigned short, (__bf16)acc[mf][nfl][1]);
        unsigned short b2 = __builtin_bit_cast(unsigned short, (__bf16)acc[mf][nfl][2]);
        unsigned short b3 = __builtin_bit_cast(unsigned short, (__bf16)acc[mf][nfl][3]);
        pv.x = (unsigned)b0 | ((unsigned)b1 << 16);
        pv.y = (unsigned)b2 | ((unsigned)b3 << 16);
        const int qloc = mf * 16 + ((l >> 4) << 2);
        *reinterpret_cast<uint2*>(reinterpret_cast<char*>(vt) + (col * 40 + qloc) * 2) = pv;
      }
    }
  __syncthreads();
  {
    const int d = tid >> 2, seg = tid & 3;
    uint4 val = *reinterpret_cast<const uint4*>(
        reinterpret_cast<const char*>(vt) + (d * 40 + seg * 8) * 2);
    *reinterpret_cast<uint4*>(VTb + (size_t)(batch * 64 + d) * NT + t0 + seg * 8) = val;
  }
}

// ---------------------------------------------------------------------------
// Kernel 2: attention segment, 32x32 MFMA, swapped QK^T (S^T = K Q^T), all
// softmax + P-layout conversion in registers (no LDS, no barriers).
// D-layout (32x32, HW-verified): col=l&31, row=(r&3)+8*(r>>2)+4*(l>>5).
__global__ __launch_bounds__(64) void sdpa_attn_seg(
    const __bf16* __restrict__ Qb, const __bf16* __restrict__ Kb,
    const __bf16* __restrict__ VTb, __bf16* __restrict__ po,
    float* __restrict__ pm, float* __restrict__ pl) {
  const int l = threadIdx.x;
  const int bid = blockIdx.x;
  const int b = bid & 7;
  const int s = bid >> 3;
  int g = 0;
#pragma unroll
  for (int gg = 1; gg < 8; ++gg)
    if (4 * gg * (gg + 1) <= s) g = gg;
  const int rem = s - 4 * g * (g + 1);
  const int qdiv = rem / (g + 1);
  const int qt = 8 * g + qdiv;
  const int seg = rem - qdiv * (g + 1);
  const int nkt = (qt >> 1) + 1;
  const int ndiag = nkt - 1;
  const int kt0 = seg * 4;
  const int kt1 = (kt0 + 4 < nkt) ? (kt0 + 4) : nkt;

  const __bf16* Qp = Qb + (size_t)b * NT * NH;
  const __bf16* Kp = Kb + (size_t)b * NT * NH;
  const __bf16* Vp = VTb + (size_t)b * NH * NT;
  const int lq = l & 31, hi = l >> 5;
  const int q0 = qt * 32;
  const int qa = q0 + lq;

  bf16x8 qf[4];
#pragma unroll
  for (int ks = 0; ks < 4; ++ks)
    qf[ks] = *reinterpret_cast<const bf16x8*>(Qp + (size_t)(q0 + lq) * NH + ks * 16 + hi * 8);

  f32x16 o0 = {}, o1 = {};
  float mreg = MINIT_VAL, lsum = 0.f;

  bf16x8 kc[8], kn[8], vv[8];
#pragma unroll
  for (int t = 0; t < 2; ++t)
#pragma unroll
    for (int ks = 0; ks < 4; ++ks)
      kc[t * 4 + ks] = *reinterpret_cast<const bf16x8*>(
          Kp + (size_t)(kt0 * 64 + 32 * t + lq) * NH + ks * 16 + hi * 8);

  for (int kt = kt0; kt < kt1; ++kt) {
    // V loads issued first; consumed after softmax (latency hidden)
#pragma unroll
    for (int dt = 0; dt < 2; ++dt)
#pragma unroll
      for (int ks = 0; ks < 4; ++ks)
        vv[dt * 4 + ks] = *reinterpret_cast<const bf16x8*>(
            Vp + (size_t)(32 * dt + lq) * NT + kt * 64 + ks * 16 + hi * 8);

    f32x16 s0 = {}, s1 = {};
#pragma unroll
    for (int ks = 0; ks < 4; ++ks)
      s0 = __builtin_amdgcn_mfma_f32_32x32x16_bf16(kc[ks], qf[ks], s0, 0, 0, 0);
#pragma unroll
    for (int ks = 0; ks < 4; ++ks)
      s1 = __builtin_amdgcn_mfma_f32_32x32x16_bf16(kc[4 + ks], qf[ks], s1, 0, 0, 0);

    const bool more = (kt + 1 < kt1);
    if (more) {                            // prefetch next K tile
#pragma unroll
      for (int t = 0; t < 2; ++t)
#pragma unroll
        for (int ks = 0; ks < 4; ++ks)
          kn[t * 4 + ks] = *reinterpret_cast<const bf16x8*>(
              Kp + (size_t)((kt + 1) * 64 + 32 * t + lq) * NH + ks * 16 + hi * 8);
    }

    if (kt == ndiag) {                     // causal mask (safe sentinel)
#pragma unroll
      for (int r = 0; r < 16; ++r) {
        const int kvr = kt * 64 + (r & 3) + 8 * (r >> 2) + 4 * hi;
        if (kvr > qa) s0[r] = MASK_VAL;
        if (kvr + 32 > qa) s1[r] = MASK_VAL;
      }
    }

    // row max: in-register tree over own 16, then cross-half shfl
    float t16[16];
#pragma unroll
    for (int r = 0; r < 16; ++r) t16[r] = fmaxf(s0[r], s1[r]);
#pragma unroll
    for (int wdt = 8; wdt > 0; wdt >>= 1)
#pragma unroll
      for (int r = 0; r < 16; ++r) if (r < wdt) t16[r] = fmaxf(t16[r], t16[r + wdt]);
    const float pmax = fmaxf(t16[0], __shfl_xor(t16[0], 32));
    const float mn = fmaxf(mreg, pmax);
    const float esc = exp2f(fminf((mreg - mn) * SOFTMAX_SC, 0.f));
    const float msc = mn * SOFTMAX_SC;
    mreg = mn;
#pragma unroll
    for (int r = 0; r < 16; ++r)
      s0[r] = exp2f(fminf(fmaf(s0[r], SOFTMAX_SC, -msc), 0.f));
#pragma unroll
    for (int r = 0; r < 16; ++r)
      s1[r] = exp2f(fminf(fmaf(s1[r], SOFTMAX_SC, -msc), 0.f));
#pragma unroll
    for (int r = 0; r < 16; ++r) t16[r] = s0[r] + s1[r];
#pragma unroll
    for (int wdt = 8; wdt > 0; wdt >>= 1)
#pragma unroll
      for (int r = 0; r < 16; ++r) if (r < wdt) t16[r] += t16[r + wdt];
    const float rs = t16[0] + __shfl_xor(t16[0], 32);
    lsum = lsum * esc + rs;
    o0 *= esc; o1 *= esc;

    // P^T (D-layout f32) -> B-fragments. Direction-proof cross-half routing:
    // own words w0..w3 hold kv pairs {4hi+0,1},{4hi+2,3},{8+4hi+0,1},{8+4hi+2,3}
    // (tile-chunk local). Need kv {8hi+0..7}: swap w2/w3 (hi=0) with w0/w1 (hi=1).
#pragma unroll
    for (int ks16 = 0; ks16 < 4; ++ks16) {
      const f32x16& pt = (ks16 < 2) ? s0 : s1;
      const int base = 8 * (ks16 & 1);
      const unsigned w0 = cvtpk(pt[base + 0], pt[base + 1]);
      const unsigned w1 = cvtpk(pt[base + 2], pt[base + 3]);
      const unsigned w2 = cvtpk(pt[base + 4], pt[base + 5]);
      const unsigned w3 = cvtpk(pt[base + 6], pt[base + 7]);
      const unsigned m_a = hi ? w0 : w2;
      const unsigned m_b = hi ? w1 : w3;
      const unsigned e_a = __shfl_xor(m_a, 32);
      const unsigned e_b = __shfl_xor(m_b, 32);
      union { unsigned u[4]; bf16x8 v; } pb;
      pb.u[0] = hi ? e_a : w0;
      pb.u[1] = hi ? e_b : w1;
      pb.u[2] = hi ? w2 : e_a;
      pb.u[3] = hi ? w3 : e_b;
      o0 = __builtin_amdgcn_mfma_f32_32x32x16_bf16(vv[ks16], pb.v, o0, 0, 0, 0);
      o1 = __builtin_amdgcn_mfma_f32_32x32x16_bf16(vv[4 + ks16], pb.v, o1, 0, 0, 0);
    }

    if (more) {
#pragma unroll
      for (int i = 0; i < 8; ++i) kc[i] = kn[i];
    }
  }

  // write partials: po[slot][q 32][d 64] bf16 (unnormalized), pm/pl per row
  const int slot = b * SEG_PER_B + s;
  __bf16* pop = po + (size_t)slot * 2048;
#pragma unroll
  for (int dt = 0; dt < 2; ++dt) {
    const f32x16& ov = dt ? o1 : o0;
#pragma unroll
    for (int u = 0; u < 4; ++u) {
      uint2 val;
      val.x = cvtpk(ov[4 * u + 0], ov[4 * u + 1]);
      val.y = cvtpk(ov[4 * u + 2], ov[4 * u + 3]);
      *reinterpret_cast<uint2*>(pop + lq * 64 + 8 * u + 4 * hi + 32 * dt) = val;
    }
  }
  if (hi == 0) {
    pm[slot * 32 + lq] = mreg;
    pl[slot * 32 + lq] = lsum;
  }
}

// ---------------------------------------------------------------------------
// Kernel 3: combine <=8 segments per q-tile (32 rows), normalize, f32 out.
__global__ __launch_bounds__(256) void sdpa_combine(
    const __bf16* __restrict__ po, const float* __restrict__ pm,
    const float* __restrict__ pl, float* __restrict__ out) {
  const int bid = blockIdx.x;              // 512: (qt<<3) | b
  const int b = bid & 7, qt = bid >> 3;
  const int g = qt >> 3, nseg = g + 1;
  const int base = b * SEG_PER_B + 4 * g * (g + 1) + (qt - 8 * g) * nseg;
  const int t = threadIdx.x;
  const int r = t >> 3, dc = (t & 7) << 3;

  float M = MASK_VAL;
  for (int s = 0; s < nseg; ++s) M = fmaxf(M, pm[(base + s) * 32 + r]);
  float L = 0.f;
  float acc[8] = {0.f, 0.f, 0.f, 0.f, 0.f, 0.f, 0.f, 0.f};
  for (int s = 0; s < nseg; ++s) {
    const int slot = base + s;
    const float w = exp2f(fminf((pm[slot * 32 + r] - M) * SOFTMAX_SC, 0.f));
    L += pl[slot * 32 + r] * w;
    const bf16x8 v = *reinterpret_cast<const bf16x8*>(po + (size_t)slot * 2048 + r * 64 + dc);
#pragma unroll
    for (int j = 0; j < 8; ++j) acc[j] += w * (float)v[j];
  }
  const float inv = 1.f / L;
  float4 v0 = {acc[0] * inv, acc[1] * inv, acc[2] * inv, acc[3] * inv};
  float4 v1 = {acc[4] * inv, acc[5] * inv, acc[6] * inv, acc[7] * inv};
  float* dst = out + ((size_t)b * NT + qt * 32 + r) * NH + dc;
  *reinterpret_cast<float4*>(dst) = v0;
  *reinterpret_cast<float4*>(dst + 4) = v1;
}

// ---------------------------------------------------------------------------
extern "C" void kernel_launch(void* const* d_in, const int* in_sizes, int n_in,
                              void* d_out, int out_size, void* d_ws, size_t ws_size,
                              hipStream_t stream) {
  const float* x  = (const float*)d_in[0];
  const float* Wq = (const float*)d_in[1];
  const float* Wk = (const float*)d_in[2];
  const float* Wv = (const float*)d_in[3];
  char* ws = (char*)d_ws;
  __bf16* wswz = (__bf16*)(ws);
  __bf16* Qb   = (__bf16*)(ws + WSWZ_BYTES);
  __bf16* Kb   = (__bf16*)(ws + WSWZ_BYTES + QK_BYTES);
  __bf16* VTb  = (__bf16*)(ws + WSWZ_BYTES + 2 * (size_t)QK_BYTES);
  __bf16* po   = (__bf16*)(ws + PO_OFF);
  float*  pm   = (float*)(ws + PM_OFF);
  float*  pl   = (float*)(ws + PL_OFF);
  float* out = (float*)d_out;

  sdpa_prep_w<<<dim3(384), dim3(64), 0, stream>>>(Wq, Wk, Wv, wswz);
  sdpa_qkv<<<dim3(512), dim3(256), 0, stream>>>(x, wswz, Qb, Kb, VTb);
  sdpa_attn_seg<<<dim3(SLOTS), dim3(64), 0, stream>>>(Qb, Kb, VTb, po, pm, pl);
  sdpa_combine<<<dim3(NB * 64), dim3(256), 0, stream>>>(po, pm, pl, out);
}